// Round 4
// baseline (138.164 us; speedup 1.0000x reference)
//
#include <hip/hip_runtime.h>

// Trilinear grid_sample (align_corners=False, zeros padding) of 256^3 fp32
// volume, scaled by 100.
//
// Round 6: LDS-staged tile gather.
//   Evidence rounds 2-5: kernel time pinned at ~42 us against 2x request
//   count, 2.4x HBM traffic, 1.7x occupancy. Every variant kept volume taps
//   as per-lane scattered VMEM requests; the random-line service path
//   (L2-hit or HBM-miss alike) saturates at ~50 G lines/s. Fix: remove the
//   taps from VMEM entirely. Bucket points by (z,y) tile (4x8 +1 halo),
//   stage the 45 KB tile into LDS with coalesced float4 reads (94 MB
//   sequential total), serve all 8 taps from LDS (random 4B @ ~69 TB/s).
//   Scattered VMEM drops from 4/pt to 1/pt (out store).

#define RES 256
#define TZ 4              // z-slices per tile
#define TY 8              // y-rows per tile
#define NZT 64            // 256/TZ
#define NYT 32            // 256/TY
#define NBKT 2048         // NZT*NYT buckets
#define CAP 318           // slots/bucket (avg 256; overflow -> direct compute)
#define NROW 45           // (TZ+1)*(TY+1) staged rows per tile
#define LDSF (NROW * 256) // floats in LDS tile

typedef float vfloat4 __attribute__((ext_vector_type(4)));

// ---- direct-path interp (verified, absmax 3.8e-6) ----

__device__ __forceinline__ void setup_c(
    float rx, float ry, float rz,
    int& r00, int& r01, int& r10, int& r11, int& xc0, int& xc1,
    float& wx0, float& wx1, float& wy0, float& wy1, float& wz0, float& wz1)
{
    float ix = ((rx * 2.0f + 1.0f) * (float)RES - 1.0f) * 0.5f;
    float iy = ((ry * 2.0f + 1.0f) * (float)RES - 1.0f) * 0.5f;
    float iz = ((rz * 2.0f + 1.0f) * (float)RES - 1.0f) * 0.5f;

    float x0f = floorf(ix), y0f = floorf(iy), z0f = floorf(iz);
    float tx = ix - x0f, ty = iy - y0f, tz = iz - z0f;

    int x0 = (int)x0f, y0 = (int)y0f, z0 = (int)z0f;
    int x1 = x0 + 1, y1 = y0 + 1, z1 = z0 + 1;

    wx0 = (x0 >= 0 && x0 < RES) ? (1.0f - tx) : 0.0f;
    wx1 = (x1 >= 0 && x1 < RES) ? tx : 0.0f;
    wy0 = (y0 >= 0 && y0 < RES) ? (1.0f - ty) : 0.0f;
    wy1 = (y1 >= 0 && y1 < RES) ? ty : 0.0f;
    wz0 = (z0 >= 0 && z0 < RES) ? (1.0f - tz) : 0.0f;
    wz1 = (z1 >= 0 && z1 < RES) ? tz : 0.0f;

    xc0 = min(max(x0, 0), RES - 1); xc1 = min(max(x1, 0), RES - 1);
    int yc0 = min(max(y0, 0), RES - 1), yc1 = min(max(y1, 0), RES - 1);
    int zc0 = min(max(z0, 0), RES - 1), zc1 = min(max(z1, 0), RES - 1);

    r00 = (zc0 * RES + yc0) * RES;
    r01 = (zc0 * RES + yc1) * RES;
    r10 = (zc1 * RES + yc0) * RES;
    r11 = (zc1 * RES + yc1) * RES;
}

__device__ __forceinline__ float trilerp_g(
    const float* __restrict__ vol,
    int r00, int r01, int r10, int r11, int xc0, int xc1,
    float wx0, float wx1, float wy0, float wy1, float wz0, float wz1)
{
    float v000 = vol[r00 + xc0];
    float v001 = vol[r00 + xc1];
    float v010 = vol[r01 + xc0];
    float v011 = vol[r01 + xc1];
    float v100 = vol[r10 + xc0];
    float v101 = vol[r10 + xc1];
    float v110 = vol[r11 + xc0];
    float v111 = vol[r11 + xc1];
    float c00 = v000 * wx0 + v001 * wx1;
    float c01 = v010 * wx0 + v011 * wx1;
    float c10 = v100 * wx0 + v101 * wx1;
    float c11 = v110 * wx0 + v111 * wx1;
    float c0 = c00 * wy0 + c01 * wy1;
    float c1 = c10 * wy0 + c11 * wy1;
    return 100.0f * (c0 * wz0 + c1 * wz1);
}

__device__ __forceinline__ float interp_point(
    const float* __restrict__ vol, float rx, float ry, float rz)
{
    int r00, r01, r10, r11, x0, x1;
    float wx0, wx1, wy0, wy1, wz0, wz1;
    setup_c(rx, ry, rz, r00, r01, r10, r11, x0, x1,
            wx0, wx1, wy0, wy1, wz0, wz1);
    return trilerp_g(vol, r00, r01, r10, r11, x0, x1,
                     wx0, wx1, wy0, wy1, wz0, wz1);
}

// ---- pass 1: bucket-scatter points by (z,y) tile ----
// block = 256 threads, 1024 points/block (4/thread).

__global__ __launch_bounds__(256) void VolumeExplicit_scatter_kernel(
    const float* __restrict__ x,
    const float* __restrict__ vol,
    float* __restrict__ out,
    vfloat4* __restrict__ sorted,
    unsigned* __restrict__ cursor)
{
    __shared__ unsigned lh[NBKT];
    __shared__ unsigned lbase[NBKT];
    int t = threadIdx.x;
    int base_i = blockIdx.x * 1024;

    for (int b = t; b < NBKT; b += 256) lh[b] = 0;
    __syncthreads();

    float px[4], py[4], pz[4];
    int bk[4];
    unsigned lr[4];
    #pragma unroll
    for (int k = 0; k < 4; ++k) {
        int i = base_i + (k << 8) + t;
        px[k] = __builtin_nontemporal_load(&x[3 * i + 0]);
        py[k] = __builtin_nontemporal_load(&x[3 * i + 1]);
        pz[k] = __builtin_nontemporal_load(&x[3 * i + 2]);
        float iy = ((py[k] * 2.0f + 1.0f) * (float)RES - 1.0f) * 0.5f;
        float iz = ((pz[k] * 2.0f + 1.0f) * (float)RES - 1.0f) * 0.5f;
        int y0 = (int)floorf(iy);
        int z0 = (int)floorf(iz);
        int yc0 = min(max(y0, 0), RES - 1);
        int zc0 = min(max(z0, 0), RES - 1);
        int b_ = (zc0 >> 2) * NYT + (yc0 >> 3);
        bk[k] = b_;
        lr[k] = atomicAdd(&lh[b_], 1u);
    }
    __syncthreads();

    for (int b = t; b < NBKT; b += 256) {
        unsigned c = lh[b];
        lbase[b] = c ? atomicAdd(&cursor[b], c) : 0u;
    }
    __syncthreads();

    #pragma unroll
    for (int k = 0; k < 4; ++k) {
        int i = base_i + (k << 8) + t;
        unsigned pos = lbase[bk[k]] + lr[k];
        if (pos < CAP) {
            vfloat4 v;
            v.x = px[k]; v.y = py[k]; v.z = pz[k];
            v.w = __uint_as_float((unsigned)i);
            sorted[bk[k] * CAP + pos] = v;
        } else {
            // overflow insurance: compute direct (correctness-safe)
            out[i] = interp_point(vol, px[k], py[k], pz[k]);
        }
    }
}

// ---- pass 2: LDS-staged tile gather ----
// grid = 2048 blocks, one per (zt,yt) tile. blockIdx%8 == XCD:
//   xcd=B&7, j=(B>>3)&7, yt=B>>6; zt = xcd*8+j -> each XCD stages only
//   z-slices [32*xcd, 32*xcd+33) (L2-friendly coalesced reads).
// Stage 45 rows (4+1 z x 8+1 y halo, clamped) x 1KB = 45 KB LDS via float4,
// then all 8 taps per point are LDS reads.

__global__ __launch_bounds__(256) void VolumeExplicit_gather_kernel(
    const vfloat4* __restrict__ sorted,
    const unsigned* __restrict__ cursor,
    const float* __restrict__ vol,
    float* __restrict__ out)
{
    __shared__ float smem[LDSF];   // 46080 B -> 3 blocks/CU

    int t = threadIdx.x;
    int B = blockIdx.x;
    int xcd = B & 7;
    int j = (B >> 3) & 7;
    int yt = B >> 6;               // 0..31
    int zt = xcd * 8 + j;          // 0..63
    int bucket = zt * NYT + yt;

    // ---- stage tile: 45 rows x 64 float4 ----
    for (int k = t; k < NROW * 64; k += 256) {
        int q = k >> 6;            // staged row 0..44
        int lane = k & 63;
        int zr = q / 9;            // 0..4
        int yr = q - zr * 9;       // 0..8
        int gz = min(zt * TZ + zr, RES - 1);
        int gy = min(yt * TY + yr, RES - 1);
        const vfloat4* src =
            reinterpret_cast<const vfloat4*>(vol + ((gz << 8) + gy) * 256);
        reinterpret_cast<vfloat4*>(smem)[(q << 6) + lane] = src[lane];
    }
    __syncthreads();

    unsigned count = cursor[bucket];
    if (count > CAP) count = CAP;

    for (int s = t; s < (int)count; s += 256) {
        vfloat4 p = __builtin_nontemporal_load(&sorted[bucket * CAP + s]);

        float ix = ((p.x * 2.0f + 1.0f) * (float)RES - 1.0f) * 0.5f;
        float iy = ((p.y * 2.0f + 1.0f) * (float)RES - 1.0f) * 0.5f;
        float iz = ((p.z * 2.0f + 1.0f) * (float)RES - 1.0f) * 0.5f;

        float x0f = floorf(ix), y0f = floorf(iy), z0f = floorf(iz);
        float tx = ix - x0f, ty = iy - y0f, tz = iz - z0f;

        int x0 = (int)x0f, y0 = (int)y0f, z0 = (int)z0f;
        int x1 = x0 + 1, y1 = y0 + 1, z1 = z0 + 1;

        float wx0 = (x0 >= 0 && x0 < RES) ? (1.0f - tx) : 0.0f;
        float wx1 = (x1 >= 0 && x1 < RES) ? tx : 0.0f;
        float wy0 = (y0 >= 0 && y0 < RES) ? (1.0f - ty) : 0.0f;
        float wy1 = (y1 >= 0 && y1 < RES) ? ty : 0.0f;
        float wz0 = (z0 >= 0 && z0 < RES) ? (1.0f - tz) : 0.0f;
        float wz1 = (z1 >= 0 && z1 < RES) ? tz : 0.0f;

        int xc0 = min(max(x0, 0), RES - 1), xc1 = min(max(x1, 0), RES - 1);
        int yc0 = min(max(y0, 0), RES - 1), yc1 = min(max(y1, 0), RES - 1);
        int zc0 = min(max(z0, 0), RES - 1), zc1 = min(max(z1, 0), RES - 1);

        // local tile coords (bucket key guarantees zc0 in [4zt,4zt+3],
        // yc0 in [8yt,8yt+7]; +1 neighbors stay inside the staged halo)
        int zl0 = zc0 - zt * TZ, zl1 = zc1 - zt * TZ;
        int yl0 = yc0 - yt * TY, yl1 = yc1 - yt * TY;

        int r00 = ((zl0 * 9 + yl0) << 8);
        int r01 = ((zl0 * 9 + yl1) << 8);
        int r10 = ((zl1 * 9 + yl0) << 8);
        int r11 = ((zl1 * 9 + yl1) << 8);

        float v000 = smem[r00 + xc0];
        float v001 = smem[r00 + xc1];
        float v010 = smem[r01 + xc0];
        float v011 = smem[r01 + xc1];
        float v100 = smem[r10 + xc0];
        float v101 = smem[r10 + xc1];
        float v110 = smem[r11 + xc0];
        float v111 = smem[r11 + xc1];

        float c00 = v000 * wx0 + v001 * wx1;
        float c01 = v010 * wx0 + v011 * wx1;
        float c10 = v100 * wx0 + v101 * wx1;
        float c11 = v110 * wx0 + v111 * wx1;
        float c0 = c00 * wy0 + c01 * wy1;
        float c1 = c10 * wy0 + c11 * wy1;
        float o = 100.0f * (c0 * wz0 + c1 * wz1);

        __builtin_nontemporal_store(o, &out[__float_as_uint(p.w)]);
    }
}

// ---- fallback: direct kernel (any shape / small workspace) ----

__global__ __launch_bounds__(256) void VolumeExplicit_29257317220866_kernel(
    const float* __restrict__ x,
    const float* __restrict__ vol,
    float* __restrict__ out,
    int n)
{
    int tid = blockIdx.x * blockDim.x + threadIdx.x;
    int half = n >> 1;
    if (tid >= half) return;
    int iA = tid;
    int iB = tid + half;

    float oA, oB;
    {
        float rx = __builtin_nontemporal_load(&x[3 * iA + 0]);
        float ry = __builtin_nontemporal_load(&x[3 * iA + 1]);
        float rz = __builtin_nontemporal_load(&x[3 * iA + 2]);
        oA = interp_point(vol, rx, ry, rz);
    }
    {
        float rx = __builtin_nontemporal_load(&x[3 * iB + 0]);
        float ry = __builtin_nontemporal_load(&x[3 * iB + 1]);
        float rz = __builtin_nontemporal_load(&x[3 * iB + 2]);
        oB = interp_point(vol, rx, ry, rz);
    }

    __builtin_nontemporal_store(oA, &out[iA]);
    __builtin_nontemporal_store(oB, &out[iB]);
}

extern "C" void kernel_launch(void* const* d_in, const int* in_sizes, int n_in,
                              void* d_out, int out_size, void* d_ws, size_t ws_size,
                              hipStream_t stream) {
    const float* x   = (const float*)d_in[0];   // [8, 65536, 3] fp32
    const float* vol = (const float*)d_in[1];   // [256,256,256] fp32
    float* out = (float*)d_out;                 // [8, 65536] fp32

    int n = out_size;                            // 524288 points
    size_t need = 8192 + (size_t)NBKT * CAP * sizeof(vfloat4);  // ~10.43 MB

    if (n == 524288 && d_ws != nullptr && ws_size >= need) {
        unsigned* cursor = (unsigned*)d_ws;               // 2048 u32 = 8 KB
        vfloat4* sorted  = (vfloat4*)((char*)d_ws + 8192);

        hipMemsetAsync(cursor, 0, NBKT * sizeof(unsigned), stream);
        VolumeExplicit_scatter_kernel<<<n / 1024, 256, 0, stream>>>(
            x, vol, out, sorted, cursor);
        VolumeExplicit_gather_kernel<<<NBKT, 256, 0, stream>>>(
            sorted, cursor, vol, out);
    } else {
        int half = n >> 1;
        int block = 256;
        int grid = (half + block - 1) / block;
        VolumeExplicit_29257317220866_kernel<<<grid, block, 0, stream>>>(x, vol, out, n);
    }
}

// Round 5
// 133.679 us; speedup vs baseline: 1.0336x; 1.0336x over previous
//
#include <hip/hip_runtime.h>

// Trilinear grid_sample (align_corners=False, zeros padding) of 256^3 fp32
// volume, scaled by 100.
//
// Round 7: persistent double-buffered LDS gather.
//   Round-6 post-mortem: LDS taps were right, schedule was wrong -- one
//   46KB stage + full barrier drain per short-lived block = barrier-chopped
//   memcpy at ~2.1 TB/s (gather ~45us). Fix: 1 persistent block/CU, 8 tiles
//   each, 2x45KB LDS buffers; stage tile k+1 via global_load_lds (width 16,
//   1KB/row/wave-instr, no VGPR roundtrip) WHILE computing tile k from the
//   other buffer; single vmcnt(0)+barrier per tile. Staging (94MB streaming)
//   should run at ~5.5 TB/s with HBM latency hidden by 45KB in flight/CU.
//   Scatter pass unchanged (verified, ~13us).

#define RES 256
#define TZ 4              // z-slices per tile
#define TY 8              // y-rows per tile
#define NZT 64            // 256/TZ
#define NYT 32            // 256/TY
#define NBKT 2048         // NZT*NYT buckets
#define CAP 352           // slots/bucket (avg 256, +6 sigma; overflow->direct)
#define NROW 45           // (TZ+1)*(TY+1) staged rows per tile
#define TILEF (NROW * 256) // floats per LDS buffer (45 KB)
#define NTHREADS 256

typedef float vfloat4 __attribute__((ext_vector_type(4)));

// ---- direct-path interp (verified, absmax 3.8e-6) ----

__device__ __forceinline__ float interp_point(
    const float* __restrict__ vol, float rx, float ry, float rz)
{
    float ix = ((rx * 2.0f + 1.0f) * (float)RES - 1.0f) * 0.5f;
    float iy = ((ry * 2.0f + 1.0f) * (float)RES - 1.0f) * 0.5f;
    float iz = ((rz * 2.0f + 1.0f) * (float)RES - 1.0f) * 0.5f;

    float x0f = floorf(ix), y0f = floorf(iy), z0f = floorf(iz);
    float tx = ix - x0f, ty = iy - y0f, tz = iz - z0f;

    int x0 = (int)x0f, y0 = (int)y0f, z0 = (int)z0f;
    int x1 = x0 + 1, y1 = y0 + 1, z1 = z0 + 1;

    float wx0 = (x0 >= 0 && x0 < RES) ? (1.0f - tx) : 0.0f;
    float wx1 = (x1 >= 0 && x1 < RES) ? tx : 0.0f;
    float wy0 = (y0 >= 0 && y0 < RES) ? (1.0f - ty) : 0.0f;
    float wy1 = (y1 >= 0 && y1 < RES) ? ty : 0.0f;
    float wz0 = (z0 >= 0 && z0 < RES) ? (1.0f - tz) : 0.0f;
    float wz1 = (z1 >= 0 && z1 < RES) ? tz : 0.0f;

    int xc0 = min(max(x0, 0), RES - 1), xc1 = min(max(x1, 0), RES - 1);
    int yc0 = min(max(y0, 0), RES - 1), yc1 = min(max(y1, 0), RES - 1);
    int zc0 = min(max(z0, 0), RES - 1), zc1 = min(max(z1, 0), RES - 1);

    int r00 = (zc0 * RES + yc0) * RES;
    int r01 = (zc0 * RES + yc1) * RES;
    int r10 = (zc1 * RES + yc0) * RES;
    int r11 = (zc1 * RES + yc1) * RES;

    float v000 = vol[r00 + xc0];
    float v001 = vol[r00 + xc1];
    float v010 = vol[r01 + xc0];
    float v011 = vol[r01 + xc1];
    float v100 = vol[r10 + xc0];
    float v101 = vol[r10 + xc1];
    float v110 = vol[r11 + xc0];
    float v111 = vol[r11 + xc1];

    float c00 = v000 * wx0 + v001 * wx1;
    float c01 = v010 * wx0 + v011 * wx1;
    float c10 = v100 * wx0 + v101 * wx1;
    float c11 = v110 * wx0 + v111 * wx1;
    float c0 = c00 * wy0 + c01 * wy1;
    float c1 = c10 * wy0 + c11 * wy1;
    return 100.0f * (c0 * wz0 + c1 * wz1);
}

// ---- pass 1: bucket-scatter points by (z,y) tile (verified round 6) ----

__global__ __launch_bounds__(256) void VolumeExplicit_scatter_kernel(
    const float* __restrict__ x,
    const float* __restrict__ vol,
    float* __restrict__ out,
    vfloat4* __restrict__ sorted,
    unsigned* __restrict__ cursor)
{
    __shared__ unsigned lh[NBKT];
    __shared__ unsigned lbase[NBKT];
    int t = threadIdx.x;
    int base_i = blockIdx.x * 1024;

    for (int b = t; b < NBKT; b += 256) lh[b] = 0;
    __syncthreads();

    float px[4], py[4], pz[4];
    int bk[4];
    unsigned lr[4];
    #pragma unroll
    for (int k = 0; k < 4; ++k) {
        int i = base_i + (k << 8) + t;
        px[k] = __builtin_nontemporal_load(&x[3 * i + 0]);
        py[k] = __builtin_nontemporal_load(&x[3 * i + 1]);
        pz[k] = __builtin_nontemporal_load(&x[3 * i + 2]);
        float iy = ((py[k] * 2.0f + 1.0f) * (float)RES - 1.0f) * 0.5f;
        float iz = ((pz[k] * 2.0f + 1.0f) * (float)RES - 1.0f) * 0.5f;
        int y0 = (int)floorf(iy);
        int z0 = (int)floorf(iz);
        int yc0 = min(max(y0, 0), RES - 1);
        int zc0 = min(max(z0, 0), RES - 1);
        int b_ = (zc0 >> 2) * NYT + (yc0 >> 3);
        bk[k] = b_;
        lr[k] = atomicAdd(&lh[b_], 1u);
    }
    __syncthreads();

    for (int b = t; b < NBKT; b += 256) {
        unsigned c = lh[b];
        lbase[b] = c ? atomicAdd(&cursor[b], c) : 0u;
    }
    __syncthreads();

    #pragma unroll
    for (int k = 0; k < 4; ++k) {
        int i = base_i + (k << 8) + t;
        unsigned pos = lbase[bk[k]] + lr[k];
        if (pos < CAP) {
            vfloat4 v;
            v.x = px[k]; v.y = py[k]; v.z = pz[k];
            v.w = __uint_as_float((unsigned)i);
            sorted[(size_t)bk[k] * CAP + pos] = v;
        } else {
            // overflow insurance: compute direct (correctness-safe)
            out[i] = interp_point(vol, px[k], py[k], pz[k]);
        }
    }
}

// ---- staging: one tile (45 rows x 1KB) via global_load_lds ----
// Each row = ONE wave-instruction: per-lane global src = row + lane*16B,
// wave-uniform LDS dst; lane data lands at dst + lane*16 (linear, matches).

__device__ __forceinline__ void stage_tile(
    const float* __restrict__ vol, float* dst, int zt, int yt, int lane, int w)
{
    for (int q = w; q < NROW; q += 4) {
        int zr = q / 9;
        int yr = q - zr * 9;
        int gz = min(zt * TZ + zr, RES - 1);
        int gy = min(yt * TY + yr, RES - 1);
        const float* src = vol + (size_t)(((gz << 8) + gy) << 8) + (lane << 2);
#if __has_builtin(__builtin_amdgcn_global_load_lds)
        __builtin_amdgcn_global_load_lds(
            (const __attribute__((address_space(1))) void*)src,
            (__attribute__((address_space(3))) void*)(dst + q * 256),
            16, 0, 0);
#else
        *(vfloat4*)(dst + q * 256 + (lane << 2)) = *(const vfloat4*)src;
#endif
    }
}

// ---- pass 2: persistent double-buffered LDS gather ----
// 256 blocks (1/CU), 8 tiles each. xcd=B&7, c=B>>3: zt=8*xcd+(c&7),
// yt = (c>>3)*8 + k, k=0..7. Stage tile k+1 while computing tile k.

__global__ __launch_bounds__(256) void VolumeExplicit_gather_kernel(
    const vfloat4* __restrict__ sorted,
    const unsigned* __restrict__ cursor,
    const float* __restrict__ vol,
    float* __restrict__ out)
{
    extern __shared__ float smem[];   // 2 * TILEF floats = 92160 B

    int t = threadIdx.x;
    int lane = t & 63;
    int w = t >> 6;                   // wave 0..3
    int B = blockIdx.x;
    int xcd = B & 7;
    int c = B >> 3;                   // 0..31
    int zt = (xcd << 3) | (c & 7);    // 0..63, pinned to this XCD's slab
    int ytBase = (c >> 3) << 3;       // 0,8,16,24

    stage_tile(vol, smem, zt, ytBase, lane, w);
    asm volatile("s_waitcnt vmcnt(0)");
    __syncthreads();

    #pragma unroll 1
    for (int k = 0; k < 8; ++k) {
        if (k < 7)
            stage_tile(vol, smem + ((k + 1) & 1) * TILEF, zt, ytBase + k + 1,
                       lane, w);

        int yt = ytBase + k;
        int bucket = zt * NYT + yt;
        unsigned count = cursor[bucket];
        if (count > CAP) count = CAP;
        const float* tile = smem + (k & 1) * TILEF;

        for (int s = t; s < (int)count; s += NTHREADS) {
            vfloat4 p = __builtin_nontemporal_load(&sorted[(size_t)bucket * CAP + s]);

            float ix = ((p.x * 2.0f + 1.0f) * (float)RES - 1.0f) * 0.5f;
            float iy = ((p.y * 2.0f + 1.0f) * (float)RES - 1.0f) * 0.5f;
            float iz = ((p.z * 2.0f + 1.0f) * (float)RES - 1.0f) * 0.5f;

            float x0f = floorf(ix), y0f = floorf(iy), z0f = floorf(iz);
            float tx = ix - x0f, ty = iy - y0f, tz = iz - z0f;

            int x0 = (int)x0f, y0 = (int)y0f, z0 = (int)z0f;
            int x1 = x0 + 1, y1 = y0 + 1, z1 = z0 + 1;

            float wx0 = (x0 >= 0 && x0 < RES) ? (1.0f - tx) : 0.0f;
            float wx1 = (x1 >= 0 && x1 < RES) ? tx : 0.0f;
            float wy0 = (y0 >= 0 && y0 < RES) ? (1.0f - ty) : 0.0f;
            float wy1 = (y1 >= 0 && y1 < RES) ? ty : 0.0f;
            float wz0 = (z0 >= 0 && z0 < RES) ? (1.0f - tz) : 0.0f;
            float wz1 = (z1 >= 0 && z1 < RES) ? tz : 0.0f;

            int xc0 = min(max(x0, 0), RES - 1), xc1 = min(max(x1, 0), RES - 1);
            int yc0 = min(max(y0, 0), RES - 1), yc1 = min(max(y1, 0), RES - 1);
            int zc0 = min(max(z0, 0), RES - 1), zc1 = min(max(z1, 0), RES - 1);

            // local tile coords (bucket key guarantees zc0 in [4zt,4zt+3],
            // yc0 in [8yt,8yt+7]; +1 neighbors stay inside the staged halo)
            int zl0 = zc0 - zt * TZ, zl1 = zc1 - zt * TZ;
            int yl0 = yc0 - yt * TY, yl1 = yc1 - yt * TY;

            int r00 = ((zl0 * 9 + yl0) << 8);
            int r01 = ((zl0 * 9 + yl1) << 8);
            int r10 = ((zl1 * 9 + yl0) << 8);
            int r11 = ((zl1 * 9 + yl1) << 8);

            float v000 = tile[r00 + xc0];
            float v001 = tile[r00 + xc1];
            float v010 = tile[r01 + xc0];
            float v011 = tile[r01 + xc1];
            float v100 = tile[r10 + xc0];
            float v101 = tile[r10 + xc1];
            float v110 = tile[r11 + xc0];
            float v111 = tile[r11 + xc1];

            float c00 = v000 * wx0 + v001 * wx1;
            float c01 = v010 * wx0 + v011 * wx1;
            float c10 = v100 * wx0 + v101 * wx1;
            float c11 = v110 * wx0 + v111 * wx1;
            float c0 = c00 * wy0 + c01 * wy1;
            float c1 = c10 * wy0 + c11 * wy1;
            float o = 100.0f * (c0 * wz0 + c1 * wz1);

            __builtin_nontemporal_store(o, &out[__float_as_uint(p.w)]);
        }

        // drain staging of tile k+1, then swap buffers
        asm volatile("s_waitcnt vmcnt(0)");
        __syncthreads();
    }
}

// ---- fallback: direct kernel (any shape / small workspace) ----

__global__ __launch_bounds__(256) void VolumeExplicit_29257317220866_kernel(
    const float* __restrict__ x,
    const float* __restrict__ vol,
    float* __restrict__ out,
    int n)
{
    int tid = blockIdx.x * blockDim.x + threadIdx.x;
    int half = n >> 1;
    if (tid >= half) return;
    int iA = tid;
    int iB = tid + half;

    float oA, oB;
    {
        float rx = __builtin_nontemporal_load(&x[3 * iA + 0]);
        float ry = __builtin_nontemporal_load(&x[3 * iA + 1]);
        float rz = __builtin_nontemporal_load(&x[3 * iA + 2]);
        oA = interp_point(vol, rx, ry, rz);
    }
    {
        float rx = __builtin_nontemporal_load(&x[3 * iB + 0]);
        float ry = __builtin_nontemporal_load(&x[3 * iB + 1]);
        float rz = __builtin_nontemporal_load(&x[3 * iB + 2]);
        oB = interp_point(vol, rx, ry, rz);
    }

    __builtin_nontemporal_store(oA, &out[iA]);
    __builtin_nontemporal_store(oB, &out[iB]);
}

extern "C" void kernel_launch(void* const* d_in, const int* in_sizes, int n_in,
                              void* d_out, int out_size, void* d_ws, size_t ws_size,
                              hipStream_t stream) {
    const float* x   = (const float*)d_in[0];   // [8, 65536, 3] fp32
    const float* vol = (const float*)d_in[1];   // [256,256,256] fp32
    float* out = (float*)d_out;                 // [8, 65536] fp32

    int n = out_size;                            // 524288 points
    size_t need = 8192 + (size_t)NBKT * CAP * sizeof(vfloat4);  // ~11.5 MB

    if (n == 524288 && d_ws != nullptr && ws_size >= need) {
        unsigned* cursor = (unsigned*)d_ws;               // 2048 u32 = 8 KB
        vfloat4* sorted  = (vfloat4*)((char*)d_ws + 8192);

        hipMemsetAsync(cursor, 0, NBKT * sizeof(unsigned), stream);
        VolumeExplicit_scatter_kernel<<<n / 1024, 256, 0, stream>>>(
            x, vol, out, sorted, cursor);
        VolumeExplicit_gather_kernel<<<256, NTHREADS,
            2 * TILEF * sizeof(float), stream>>>(sorted, cursor, vol, out);
    } else {
        int half = n >> 1;
        int block = 256;
        int grid = (half + block - 1) / block;
        VolumeExplicit_29257317220866_kernel<<<grid, block, 0, stream>>>(x, vol, out, n);
    }
}